// Round 9
// baseline (218.488 us; speedup 1.0000x reference)
//
#include <hip/hip_runtime.h>
#include <hip/hip_fp16.h>

typedef _Float16 f16;
typedef _Float16 f16x4 __attribute__((ext_vector_type(4)));
typedef _Float16 f16x8 __attribute__((ext_vector_type(8)));
typedef float    f32x4 __attribute__((ext_vector_type(4)));

constexpr int TREES = 16;
constexpr int NNODE = 255;
constexpr int NCLS  = 100;
constexpr int NCPAD = 112;
constexpr int NB    = 8192;
constexpr int DF    = 1024;
constexpr int KTOT  = TREES * 256;   // 4096

// workspace layout (half-element offsets)
constexpr size_t XH_OFF = 0;                                    // [8192][1024] f16
constexpr size_t WH_OFF = XH_OFF + (size_t)NB * DF;             // [16][256][1024] f16
constexpr size_t SD_OFF = WH_OFF + (size_t)TREES * 256 * DF;    // [112][4096] f16
constexpr size_t BP_OFF = SD_OFF + (size_t)NCPAD * KTOT;        // [16][256] f32 padded bias
constexpr size_t PT_OFF_F = (BP_OFF + 8192) / 2;                // [16][8192][100] f32 partials

#define WAIT_VMCNT(n) asm volatile("s_waitcnt vmcnt(" #n ")" ::: "memory")
__device__ __forceinline__ void BAR() {
  asm volatile("" ::: "memory");
  __builtin_amdgcn_s_barrier();
  asm volatile("" ::: "memory");
}

__device__ __forceinline__ void gload_lds16(const f16* g, f16* l) {
  __builtin_amdgcn_global_load_lds(
      (const __attribute__((address_space(1))) void*)g,
      (__attribute__((address_space(3))) void*)l, 16, 0, 0);
}

// ---------------- merged prep: x-cvt, w-cvt, leaf-softmax, bias-pad ----------------
__global__ void prep_all_k(const float* __restrict__ x, const float* __restrict__ w,
                           const float* __restrict__ ll, const float* __restrict__ twin,
                           const float* __restrict__ sb,
                           f16* __restrict__ xh, f16* __restrict__ wh,
                           f16* __restrict__ sdt, float* __restrict__ bp) {
  int bid = blockIdx.x;
  if (bid < 4096) {
    int i = bid * 256 + threadIdx.x;
    const float4* s = (const float4*)x + (size_t)i * 2;
    float4 u = s[0], v = s[1];
    f16x8 h = {(f16)u.x, (f16)u.y, (f16)u.z, (f16)u.w,
               (f16)v.x, (f16)v.y, (f16)v.z, (f16)v.w};
    *((f16x8*)xh + i) = h;
  } else if (bid < 6144) {
    int i = (bid - 4096) * 256 + threadIdx.x;
    int flat = i * 8;
    int t = flat >> 18;
    int r = (flat >> 10) & 255;
    int k = flat & 1023;
    f16x8 h;
    if (r < NNODE) {
      const float4* s = (const float4*)(w + ((size_t)(t * NNODE + r) * DF + k));
      float4 u = s[0], v = s[1];
      h = (f16x8){(f16)u.x, (f16)u.y, (f16)u.z, (f16)u.w,
                  (f16)v.x, (f16)v.y, (f16)v.z, (f16)v.w};
    } else {
      h = (f16x8){(f16)0.f, (f16)0.f, (f16)0.f, (f16)0.f,
                  (f16)0.f, (f16)0.f, (f16)0.f, (f16)0.f};
    }
    *((f16x8*)wh + i) = h;
  } else {
    int wv   = threadIdx.x >> 6;
    int lane = threadIdx.x & 63;
    int id   = (bid - 6144) * 4 + wv;    // 0..4095 = t*256 + node
    int t    = id >> 8;
    int node = id & 255;

    float wm = -1e30f;
#pragma unroll
    for (int i = 0; i < 16; ++i) wm = fmaxf(wm, twin[i]);
    float wsum = 0.f;
#pragma unroll
    for (int i = 0; i < 16; ++i) wsum += __expf(twin[i] - wm);
    float wt = __expf(twin[t] - wm) / wsum;

    const float* rowp = ll + (size_t)id * NCLS;
    float v1 = rowp[lane];
    bool has2 = (lane + 64) < NCLS;
    float v2 = has2 ? rowp[lane + 64] : -1e30f;
    float mx = fmaxf(v1, v2);
#pragma unroll
    for (int m = 32; m; m >>= 1) mx = fmaxf(mx, __shfl_xor(mx, m, 64));
    float e1 = __expf(v1 - mx);
    float e2 = has2 ? __expf(v2 - mx) : 0.f;
    float ss = e1 + e2;
#pragma unroll
    for (int m = 32; m; m >>= 1) ss += __shfl_xor(ss, m, 64);
    float inv = wt / ss;

    sdt[(size_t)lane * KTOT + id] = (f16)(e1 * inv);
    if (lane + 64 < NCPAD)
      sdt[(size_t)(lane + 64) * KTOT + id] = has2 ? (f16)(e2 * inv) : (f16)0.f;
    if (lane == 0) bp[id] = (node < NNODE) ? sb[(size_t)t * NNODE + node] : 0.f;
  }
}

// ---------------- fused 256x256 8-wave GEMM + sigmoid + mu + leaf-GEMM ----------------
// Main loop: BK=64 in 2 k-halves, dbuf 2x64KB, 2 phases/tile.
// Phase (kt,kh): { stage A+B k-half of kt+1 (4 gloads); vmcnt(8) counted; BAR;
//   12 ds_read_b128; setprio(1) 32 MFMA setprio(0); BAR }.  Never vmcnt(0) in loop.
// Swizzle within a half: byte = (r*64 + k'*2) ^ ((r&7)<<4) (bijective, 2-way banks).
__global__ __launch_bounds__(512, 2) void tree_gemm1(
    const f16* __restrict__ xh, const f16* __restrict__ wh,
    const float* __restrict__ biasp, const f16* __restrict__ sdt,
    float* __restrict__ ptree) {
  __shared__ f16 smem[81920];  // 160 KiB (main loop uses first 128 KiB)
  char* smb = (char*)smem;

  const int tid  = threadIdx.x;
  const int lane = tid & 63;
  const int wid  = tid >> 6;
  const int l15  = lane & 15;
  const int lq   = lane >> 4;
  const int wrow = (wid >> 2) * 128;
  const int wcol = (wid & 3) * 64;

  // XCD rectangle decode: each XCD gets 8 trees x 8 row-blocks
  int bid  = blockIdx.x;
  int xcd  = bid & 7;
  int idx  = bid >> 3;
  int t    = (xcd & 1) * 8 + (idx & 7);
  int brow = (xcd >> 1) * 8 + (idx >> 3);

  const f16* xsrc = xh + (size_t)brow * 256 * DF;
  const f16* wsrc = wh + (size_t)t * 256 * DF;

  // stage A+B k-half kh of tile kt into buf (kt&1). dst linear; src inverse-swizzled.
  // inverse of byte=(r*64+cs*16)^((r&7)<<4): r0=b6^b8, r1=b7, r2=b8, cs=b4^r0 | (b5^r1)<<1
  auto stage_AB = [&](int kt, int kh) {
    int cb = kt & 1;
    const f16* asrcb = xsrc + kt * 64 + kh * 32;
    const f16* bsrcb = wsrc + kt * 64 + kh * 32;
    f16* adst = smem + cb * 32768 + kh * 8192;    // half-elem offsets
    f16* bdst = adst + 16384;
#pragma unroll
    for (int ch = 0; ch < 2; ++ch) {
      int u  = ch * 512 + tid;                  // 16B unit, 0..1023
      int r0 = ((u >> 2) ^ (u >> 4)) & 1;
      int r1 = (u >> 3) & 1;
      int r2 = (u >> 4) & 1;
      int r  = r0 | (r1 << 1) | (r2 << 2) | ((u >> 5) << 3);
      int cs = ((u ^ r0) & 1) | ((((u >> 1) ^ r1) & 1) << 1);
      gload_lds16(asrcb + (size_t)r * DF + cs * 8, adst + u * 8);
      gload_lds16(bsrcb + (size_t)r * DF + cs * 8, bdst + u * 8);
    }
  };

  // sdt prefetch rows 0..63 into S=[0,32K) — exactly 4 gloads (kt=15 ballast)
  auto sdt_stage4 = [&]() {
#pragma unroll
    for (int ch = 0; ch < 4; ++ch) {
      int q  = ch * 512 + tid;
      int rr = q >> 5;
      int jj = q & 31;
      gload_lds16(sdt + (size_t)rr * KTOT + t * 256 + ((jj * 8) ^ ((rr & 7) << 3)),
                  smem + q * 8);
    }
  };

  auto ldop = [&](const char* half_base, int row) -> f16x8 {
    return *(const f16x8*)(half_base + ((row * 64 + lq * 16) ^ ((row & 7) << 4)));
  };

  f32x4 acc[8][4];
#pragma unroll
  for (int m = 0; m < 8; ++m)
#pragma unroll
    for (int n = 0; n < 4; ++n) acc[m][n] = (f32x4){0.f, 0.f, 0.f, 0.f};

  // prologue: stage tile 0 (both k-halves) into buf 0 -> 8 loads in flight
  stage_AB(0, 0);
  stage_AB(0, 1);

  for (int kt = 0; kt < 16; ++kt) {
    const char* Acur = smb + (kt & 1) * 65536;
    const char* Bcur = Acur + 32768;
#pragma unroll
    for (int kh = 0; kh < 2; ++kh) {
      if (kt < 15)      stage_AB(kt + 1, kh);
      else if (kh == 0) sdt_stage4();
      if (kt < 15 || kh == 0) { WAIT_VMCNT(8); }
      else                    { WAIT_VMCNT(4); }
      BAR();
      const char* Ah = Acur + kh * 16384;
      const char* Bh = Bcur + kh * 16384;
      f16x8 af[8], bf[4];
#pragma unroll
      for (int m = 0; m < 8; ++m) af[m] = ldop(Ah, wrow + m * 16 + l15);
#pragma unroll
      for (int n = 0; n < 4; ++n) bf[n] = ldop(Bh, wcol + n * 16 + l15);
      __builtin_amdgcn_s_setprio(1);
#pragma unroll
      for (int m = 0; m < 8; ++m)
#pragma unroll
        for (int n = 0; n < 4; ++n)
          acc[m][n] = __builtin_amdgcn_mfma_f32_16x16x32_f16(bf[n], af[m], acc[m][n], 0, 0, 0);
      __builtin_amdgcn_s_setprio(0);
      BAR();
    }
  }

  // epilogue LDS regions: S=[0,32K) sdt (rows 0-63 already in flight),
  // U=[32K,96K) mu, P=[96K,160K) probs
  char* Sb = smb;
  char* Ub = smb + 32768;
  char* Pb = smb + 98304;

  auto stage_sdt = [&](int c0, int nrows) {
    int nch = nrows * 32;
    for (int q = tid; q < nch; q += 512) {
      int rr = q >> 5;
      int jj = q & 31;
      gload_lds16(sdt + (size_t)(c0 + rr) * KTOT + t * 256 + ((jj * 8) ^ ((rr & 7) << 3)),
                  smem + q * 8);
    }
  };

  // ---- sigmoid + bias, packed f16x4 (regs = 4 consecutive nodes per row) ----
  f16x4 ph[8][4];
#pragma unroll
  for (int m = 0; m < 8; ++m) {
#pragma unroll
    for (int n = 0; n < 4; ++n) {
      int col = wcol + n * 16 + lq * 4;
      float4 b4 = *(const float4*)(biasp + t * 256 + col);
#pragma unroll
      for (int reg = 0; reg < 4; ++reg) {
        float bv = (reg == 0) ? b4.x : (reg == 1) ? b4.y : (reg == 2) ? b4.z : b4.w;
        float z = acc[m][n][reg] + bv;
        ph[m][n][reg] = (f16)__builtin_amdgcn_rcpf(1.f + __expf(-z));
      }
    }
  }

  for (int h = 0; h < 2; ++h) {
    // P[128][256] f16, 16B-granularity swizzle: byte = (r*512 + node*2) ^ ((r&7)<<4)
    if ((wid >> 2) == h) {
#pragma unroll
      for (int m = 0; m < 8; ++m) {
#pragma unroll
        for (int n = 0; n < 4; ++n) {
          int r = m * 16 + l15;
          int nodeb = (wcol + n * 16 + lq * 4) * 2;
          *(f16x4*)(Pb + ((r * 512 + nodeb) ^ ((r & 7) << 4))) = ph[m][n];
        }
      }
    }
    __syncthreads();

    // ---- mu pass: 512 thr = 128 rows x 4 chunks; vectorized P reads ----
    {
      int r = tid >> 2;
      int c = tid & 3;
      auto PRs = [&](int node) -> float {
        return (float)*(const f16*)(Pb + ((r * 512 + node * 2) ^ ((r & 7) << 4)));
      };
      auto V8 = [&](int node) -> f16x8 {   // node must be multiple of 8
        return *(const f16x8*)(Pb + ((r * 512 + node * 2) ^ ((r & 7) << 4)));
      };
      float p0 = PRs(0);
      float p1 = PRs(1 + (c >> 1));
      float pr = ((c >> 1) ? p0 : 1.f - p0) * ((c & 1) ? p1 : 1.f - p1);
      float p2 = PRs(3 + c);
      float cur[64];
      {
        float mp = pr * p2;
        cur[1] = mp; cur[0] = pr - mp;
      }
      { // d=3: nodes 7+2c, 8+2c
        float q0 = PRs(7 + 2 * c), q1 = PRs(8 + 2 * c);
        float m1 = cur[1], mp1 = m1 * q1;
        cur[3] = mp1; cur[2] = m1 - mp1;
        float m0 = cur[0], mp0 = m0 * q0;
        cur[1] = mp0; cur[0] = m0 - mp0;
      }
      { // d=4: nodes 15+4c .. 18+4c
        float q[4];
        q[0] = PRs(15 + 4 * c);
        f16x4 v = *(const f16x4*)(Pb + ((r * 512 + (16 + 4 * c) * 2) ^ ((r & 7) << 4)));
        q[1] = (float)v[0]; q[2] = (float)v[1]; q[3] = (float)v[2];
#pragma unroll
        for (int i = 3; i >= 0; --i) {
          float mv = cur[i], mp = mv * q[i];
          cur[2 * i + 1] = mp; cur[2 * i] = mv - mp;
        }
      }
      { // d=5: nodes 31+8c .. 38+8c
        float q[8];
        q[0] = PRs(31 + 8 * c);
        f16x8 v = V8(32 + 8 * c);
#pragma unroll
        for (int j = 0; j < 7; ++j) q[j + 1] = (float)v[j];
#pragma unroll
        for (int i = 7; i >= 0; --i) {
          float mv = cur[i], mp = mv * q[i];
          cur[2 * i + 1] = mp; cur[2 * i] = mv - mp;
        }
      }
      { // d=6: nodes 63+16c .. 78+16c
        float q[16];
        q[0] = PRs(63 + 16 * c);
        f16x8 v0 = V8(64 + 16 * c), v1 = V8(72 + 16 * c);
#pragma unroll
        for (int j = 0; j < 8; ++j) q[j + 1] = (float)v0[j];
#pragma unroll
        for (int j = 0; j < 7; ++j) q[j + 9] = (float)v1[j];
#pragma unroll
        for (int i = 15; i >= 0; --i) {
          float mv = cur[i], mp = mv * q[i];
          cur[2 * i + 1] = mp; cur[2 * i] = mv - mp;
        }
      }
      { // d=7: nodes 127+32c .. 158+32c
        float q[32];
        q[0] = PRs(127 + 32 * c);
        f16x8 v0 = V8(128 + 32 * c), v1 = V8(136 + 32 * c);
        f16x8 v2 = V8(144 + 32 * c), v3 = V8(152 + 32 * c);
#pragma unroll
        for (int j = 0; j < 8; ++j) q[j + 1]  = (float)v0[j];
#pragma unroll
        for (int j = 0; j < 8; ++j) q[j + 9]  = (float)v1[j];
#pragma unroll
        for (int j = 0; j < 8; ++j) q[j + 17] = (float)v2[j];
#pragma unroll
        for (int j = 0; j < 7; ++j) q[j + 25] = (float)v3[j];
#pragma unroll
        for (int i = 31; i >= 0; --i) {
          float mv = cur[i], mp = mv * q[i];
          cur[2 * i + 1] = mp; cur[2 * i] = mv - mp;
        }
      }
      // write mu -> U [128][256] f16, swizzle (r&7)<<4
#pragma unroll
      for (int g = 0; g < 8; ++g) {
        f16x8 v;
#pragma unroll
        for (int jj = 0; jj < 8; ++jj) v[jj] = (f16)cur[g * 8 + jj];
        *(f16x8*)(Ub + ((r * 512 + c * 128 + g * 16) ^ ((r & 7) << 4))) = v;
      }
    }
    WAIT_VMCNT(0);      // S rows 0-63 arrived (own wave's loads)
    __syncthreads();    // all waves: S landed + U visible

    // ---- leaf-GEMM: out(128x112) = mu(128x256) @ sdt_t(112x256) ----
    f32x4 acc2[7];
#pragma unroll
    for (int n = 0; n < 7; ++n) acc2[n] = (f32x4){0.f, 0.f, 0.f, 0.f};
    int arow = wid * 16 + l15;

    // hoist A-frags: read mu row once (8 b128), reuse across all 7 n-tiles
    f16x8 a8[8];
#pragma unroll
    for (int s = 0; s < 8; ++s)
      a8[s] = *(const f16x8*)(Ub + ((arow * 512 + s * 64 + lq * 16) ^ ((arow & 7) << 4)));

#pragma unroll
    for (int s = 0; s < 8; ++s) {
#pragma unroll
      for (int n = 0; n < 4; ++n) {
        int br = n * 16 + l15;
        f16x8 b = *(const f16x8*)(Sb + ((br * 512 + s * 64 + lq * 16) ^ ((br & 7) << 4)));
        acc2[n] = __builtin_amdgcn_mfma_f32_16x16x32_f16(a8[s], b, acc2[n], 0, 0, 0);
      }
    }
    __syncthreads();          // S rows 0..63 reads done
    stage_sdt(64, 48);        // S rows 64..111 (rebased at S[0])
    WAIT_VMCNT(0);
    __syncthreads();
#pragma unroll
    for (int s = 0; s < 8; ++s) {
#pragma unroll
      for (int n = 4; n < 7; ++n) {
        int br = (n - 4) * 16 + l15;
        f16x8 b = *(const f16x8*)(Sb + ((br * 512 + s * 64 + lq * 16) ^ ((br & 7) << 4)));
        acc2[n] = __builtin_amdgcn_mfma_f32_16x16x32_f16(a8[s], b, acc2[n], 0, 0, 0);
      }
    }

    float* pt = ptree + ((size_t)t * NB + brow * 256 + h * 128) * NCLS;
#pragma unroll
    for (int n = 0; n < 7; ++n) {
      int col = n * 16 + l15;
      if (col < NCLS) {
#pragma unroll
        for (int reg = 0; reg < 4; ++reg) {
          int r = wid * 16 + lq * 4 + reg;
          pt[(size_t)r * NCLS + col] = acc2[n][reg];
        }
      }
    }
    if (h == 0) {
      __syncthreads();        // S reads + P reads of half 0 complete everywhere
      stage_sdt(0, 64);       // re-issue S rows 0..63 for half 1
    }
  }
}

// ---------------- reduce over trees ----------------
__global__ void reduce_k(const float* __restrict__ pt, float* __restrict__ out) {
  int i = blockIdx.x * 256 + threadIdx.x;
  constexpr size_t STRIDE4 = (size_t)NB * NCLS / 4;
  const float4* p = (const float4*)pt + i;
  float4 s = p[0];
#pragma unroll
  for (int t = 1; t < TREES; ++t) {
    float4 v = p[t * STRIDE4];
    s.x += v.x; s.y += v.y; s.z += v.z; s.w += v.w;
  }
  ((float4*)out)[i] = s;
}

// ---------------- launch ----------------
extern "C" void kernel_launch(void* const* d_in, const int* in_sizes, int n_in,
                              void* d_out, int out_size, void* d_ws, size_t ws_size,
                              hipStream_t stream) {
  const float* x  = (const float*)d_in[0];
  const float* sw = (const float*)d_in[1];
  const float* sb = (const float*)d_in[2];
  const float* ll = (const float*)d_in[3];
  const float* tw = (const float*)d_in[4];
  float* out = (float*)d_out;

  f16* ws  = (f16*)d_ws;
  f16* xh  = ws + XH_OFF;
  f16* wh  = ws + WH_OFF;
  f16* sdt = ws + SD_OFF;
  float* biasp = (float*)(ws + BP_OFF);
  float* ptree = (float*)d_ws + PT_OFF_F;

  prep_all_k<<<7168, 256, 0, stream>>>(x, sw, ll, tw, sb, xh, wh, sdt, biasp);
  tree_gemm1<<<512, 512, 0, stream>>>(xh, wh, biasp, sdt, ptree);
  reduce_k<<<(NB * NCLS / 4) / 256, 256, 0, stream>>>(ptree, out);
}